// Round 5
// baseline (2042.686 us; speedup 1.0000x reference)
//
#include <hip/hip_runtime.h>
#include <hip/hip_bf16.h>
#include <math.h>

// NEZHA-style 4-layer encoder, B=16 S=512 D=768 H=12 DH=64 FF=3072.
// Reference dtypes: float32 in / float32 out. Internal compute: bf16 MFMA.
// R3: m97-style 128x128 LDS-staged GEMM for the big GEMMs; fused QKV.
// R4/R6: fused attention middle (scores + rel gather + softmax + Prow + PV).
// R7: XCD-chunked grid (FETCH 120->20.7MB, attn 247->160us) -- but still
//     latency-bound: 0.9 waves/SIMD, 16 lockstep barrier-drains in K-loop.
// R8: attn_fused de-latency: 1 wave/block (barriers ~free, waves drift ->
//     pipes co-schedule), K read direct from L2 (no LDS staging, no drains),
//     LDS 52.7->22.3KB => 7 blocks/CU.  gemm128 et al unchanged.

typedef __bf16 bf16x8 __attribute__((ext_vector_type(8)));
typedef __bf16 bf16x4 __attribute__((ext_vector_type(4)));
typedef float  floatx4 __attribute__((ext_vector_type(4)));

constexpr int Bb = 16, Ss = 512, Dd = 768, Hh = 12, DH = 64, FF = 3072, Ll = 4;
constexpr int BH  = Bb * Hh;       // 192 (batch*heads)
constexpr int RLD = 160;           // padded rel-bucket dim (129 -> 160)
constexpr int PLD = Ss + RLD;      // 672: [V^T | T^T] inner dim
constexpr float LN_EPS = 1e-12f;

__device__ inline float wredsum(float v) {
#pragma unroll
  for (int o = 32; o > 0; o >>= 1) v += __shfl_xor(v, o, 64);
  return v;
}

__device__ inline void gload_lds16(const __bf16* gp, __bf16* lp) {
  __builtin_amdgcn_global_load_lds(
      (const __attribute__((address_space(1))) void*)gp,
      (__attribute__((address_space(3))) void*)lp, 16, 0, 0);
}

enum { E_QKV, E_RES, E_GELU };

// ---------------------------------------------------------------------------
// m97-style LDS-staged GEMM: C(M,N) = A(M,K) @ B(N,K)^T.  Block = 256 thr =
// 4 waves; 128x128 C-tile; each wave 64x64 (4x4 MFMA 16x16x32 acc).  BK=64
// staged via global_load_lds dwordx4 (wave-uniform LDS base + lane*16).
// Fragment maps (HW-verified): A/B row = lane&15, k = (lane>>4)*8+j;
// C/D col = lane&15, row = (lane>>4)*4+r.
// Grid is always a multiple of 8 -> XCD-chunked swizzle is bijective.
// ---------------------------------------------------------------------------
template <int EPI, int N, int K>
__global__ __launch_bounds__(256) void gemm128(
    const __bf16* __restrict__ A, const __bf16* __restrict__ B,
    const float* __restrict__ b0, const float* __restrict__ b1,
    const float* __restrict__ b2, const __bf16* __restrict__ aux,
    __bf16* __restrict__ o0, __bf16* __restrict__ o1, __bf16* __restrict__ o2)
{
  __shared__ __bf16 As[128 * 64];
  __shared__ __bf16 Bs[128 * 64];
  const int t = threadIdx.x;
  const int lane = t & 63, wid = t >> 6;
  constexpr int NT = N / 128;
  const int nwg = (int)gridDim.x;
  const int cpx = nwg >> 3;
  const int bid = (int)blockIdx.x;
  const int swz = (bid & 7) * cpx + (bid >> 3);
  const int tm = swz / NT, tn = swz % NT;

  const __bf16* Ag = A + (size_t)(tm * 128) * K;
  const __bf16* Bg = B + (size_t)(tn * 128) * K;

  const int srow = t >> 3;          // 0..31: staged row within 32-row chunk
  const int scol = (t & 7) * 8;     // k-offset of this thread's 16B

  const int wm = (wid >> 1) * 64, wn = (wid & 1) * 64;
  const int fr = lane & 15, fk = (lane >> 4) * 8;

  floatx4 acc[4][4] = {};

  for (int k0 = 0; k0 < K; k0 += 64) {
    __syncthreads();
#pragma unroll
    for (int j = 0; j < 4; ++j) {
      const int row = j * 32 + srow;
      const int ldsrow = j * 32 + wid * 8;              // wave-uniform base row
      gload_lds16(Ag + (size_t)row * K + k0 + scol, As + ldsrow * 64);
      gload_lds16(Bg + (size_t)row * K + k0 + scol, Bs + ldsrow * 64);
    }
    __syncthreads();
#pragma unroll
    for (int kk = 0; kk < 64; kk += 32) {
      bf16x8 af[4], bfv[4];
#pragma unroll
      for (int i = 0; i < 4; ++i) {
        af[i]  = *(const bf16x8*)(As + (wm + i * 16 + fr) * 64 + kk + fk);
        bfv[i] = *(const bf16x8*)(Bs + (wn + i * 16 + fr) * 64 + kk + fk);
      }
#pragma unroll
      for (int i = 0; i < 4; ++i)
#pragma unroll
        for (int j = 0; j < 4; ++j)
          acc[i][j] = __builtin_amdgcn_mfma_f32_16x16x32_bf16(af[i], bfv[j],
                                                              acc[i][j], 0, 0, 0);
    }
  }

  const int rbase = (lane >> 4) << 2;
  const int cl = lane & 15;

  if constexpr (EPI == E_QKV) {
    // N = 2304 = [Q(768) | K(768) | V(768)]; 128-tiles never cross a 768 edge.
    const int which = (tn * 128) / Dd;
    const float* bias = which == 0 ? b0 : (which == 1 ? b1 : b2);
#pragma unroll
    for (int j = 0; j < 4; ++j) {
      const int col = tn * 128 + wn + j * 16 + cl - which * Dd;
      const float bv = bias[col];
#pragma unroll
      for (int i = 0; i < 4; ++i)
#pragma unroll
        for (int r = 0; r < 4; ++r) {
          const int m = tm * 128 + wm + i * 16 + rbase + r;
          const float v = acc[i][j][r] + bv;
          if (which == 2) {   // V -> transposed [V^T | T^T] layout
            const int hh = col >> 6, d = col & 63;
            const int bb = m >> 9, s = m & 511;
            o2[((size_t)(bb * Hh + hh) * DH + d) * PLD + s] = (__bf16)v;
          } else {
            (which == 0 ? o0 : o1)[(size_t)m * Dd + col] = (__bf16)v;
          }
        }
    }
  } else if constexpr (EPI == E_RES) {
#pragma unroll
    for (int j = 0; j < 4; ++j) {
      const int n = tn * 128 + wn + j * 16 + cl;
      const float bv = b0[n];
#pragma unroll
      for (int i = 0; i < 4; ++i)
#pragma unroll
        for (int r = 0; r < 4; ++r) {
          const int m = tm * 128 + wm + i * 16 + rbase + r;
          o0[(size_t)m * Dd + n] =
              (__bf16)(acc[i][j][r] + bv + (float)aux[(size_t)m * Dd + n]);
        }
    }
  } else if constexpr (EPI == E_GELU) {
#pragma unroll
    for (int j = 0; j < 4; ++j) {
      const int n = tn * 128 + wn + j * 16 + cl;
      const float bv = b0[n];
#pragma unroll
      for (int i = 0; i < 4; ++i)
#pragma unroll
        for (int r = 0; r < 4; ++r) {
          const int m = tm * 128 + wm + i * 16 + rbase + r;
          const float x = acc[i][j][r] + bv;
          o0[(size_t)m * FF + n] =
              (__bf16)(0.5f * x * (1.0f + erff(x * 0.7071067811865475f)));
        }
    }
  }
}

// ---------------------------------------------------------------------------
// Fused attention middle.  Grid = 6144 1-D, 64 thr = ONE wave per block
// (barriers ~free; waves drift across phases -> MFMA/mem pipes co-schedule).
// XCD-chunked: swz = (bid&7)*768 + bid>>3; qt = swz&31, bh = swz>>5 ->
// 24 consecutive bh per XCD => K/vte slices L2-resident (proven R7: FETCH
// dropped to unique traffic).  Wave owns q rows [qt*16, +16).
//   R   = Q @ Tb^T            (24 MFMAs)  -> Pl ext cols 512..643
//   S   = Q @ K^T             (64 MFMAs)  -- K read DIRECT from L2, fully
//         unrolled so the compiler keeps many loads in flight (no barriers)
//   S   = (S + R[bucket]) * 0.125 + mask_bias
//   softmax in-register; tail buckets predicated in the same pass
//   P interior + tails + gather -> Pl
//   ctx = P_ext @ vte^T over K=672 (84 MFMAs), vte loads pipelined 2-deep
// LDS = 16*696*2 = 22.3 KB -> 7 blocks/CU.
// ---------------------------------------------------------------------------
__global__ __launch_bounds__(64) void attn_fused(
    const __bf16* __restrict__ Q, const __bf16* __restrict__ Kb,
    const __bf16* __restrict__ Vt, const __bf16* __restrict__ Tb,
    const int* __restrict__ mask, __bf16* __restrict__ out)
{
  __shared__ __bf16 Pl[16][696];      // stride 696 -> 2-way banks (free)

  const int lane = threadIdx.x & 63;
  const int cl = lane & 15, g = lane >> 4;
  const int bid = (int)blockIdx.x;
  const int swz = (bid & 7) * (6144 / 8) + (bid >> 3);
  const int qt = swz & 31, bh = swz >> 5;
  const int b = bh / Hh, h = bh % Hh;
  const int qb0 = qt * 16;

  // Q fragments (A operand): row = cl, k = g*8 + j (kk=0) / +32 (kk=1)
  const __bf16* qp = Q + (size_t)(b * Ss + qb0 + cl) * Dd + h * DH + g * 8;
  const bf16x8 aq0 = *(const bf16x8*)qp;
  const bf16x8 aq1 = *(const bf16x8*)(qp + 32);

  // ---- R = Q @ Tb^T (Tb: 192 rows x 64, rows >=129 are zero) ----
  {
    floatx4 rac[12] = {};
#pragma unroll
    for (int tt = 0; tt < 12; ++tt) {
      const __bf16* bp = Tb + (size_t)(tt * 16 + cl) * DH + g * 8;
      const bf16x8 b0 = *(const bf16x8*)bp;
      const bf16x8 b1 = *(const bf16x8*)(bp + 32);
      rac[tt] = __builtin_amdgcn_mfma_f32_16x16x32_bf16(aq0, b0, rac[tt], 0, 0, 0);
      rac[tt] = __builtin_amdgcn_mfma_f32_16x16x32_bf16(aq1, b1, rac[tt], 0, 0, 0);
    }
#pragma unroll
    for (int tt = 0; tt < 12; ++tt) {
      const int col = tt * 16 + cl;
      if (col < 132) {
#pragma unroll
        for (int r = 0; r < 4; ++r) Pl[g * 4 + r][Ss + col] = (__bf16)rac[tt][r];
      }
    }
  }
  __syncthreads();   // R visible (single-wave: ~free, orders LDS)

  // ---- scores S = Q @ K^T, K direct from global (L2-resident) ----
  floatx4 sac[32] = {};
  const __bf16* kbase = Kb + (size_t)(b * Ss) * Dd + h * DH + g * 8;
  __builtin_amdgcn_s_setprio(1);
#pragma unroll
  for (int tt = 0; tt < 32; ++tt) {
    const __bf16* kp = kbase + (size_t)(tt * 16 + cl) * Dd;
    const bf16x8 b0 = *(const bf16x8*)kp;
    const bf16x8 b1 = *(const bf16x8*)(kp + 32);
    sac[tt] = __builtin_amdgcn_mfma_f32_16x16x32_bf16(aq0, b0, sac[tt], 0, 0, 0);
    sac[tt] = __builtin_amdgcn_mfma_f32_16x16x32_bf16(aq1, b1, sac[tt], 0, 0, 0);
  }
  __builtin_amdgcn_s_setprio(0);

  // ---- rel gather + scale + mask; row max ----
  float mxv[4], smv[4], t0a[4], t1a[4];
#pragma unroll
  for (int r = 0; r < 4; ++r) { mxv[r] = -3.0e38f; smv[r] = t0a[r] = t1a[r] = 0.f; }
#pragma unroll
  for (int tt = 0; tt < 32; ++tt) {
    const int k = tt * 16 + cl;
    const float mbk = (1.0f - (float)mask[b * Ss + k]) * -10000.0f;
#pragma unroll
    for (int r = 0; r < 4; ++r) {
      const int ql = g * 4 + r;
      int rr = k - (qb0 + ql);
      rr = rr < -64 ? -64 : (rr > 64 ? 64 : rr);
      const float s = (sac[tt][r] + (float)Pl[ql][Ss + rr + 64]) * 0.125f + mbk;
      sac[tt][r] = s;
      mxv[r] = fmaxf(mxv[r], s);
    }
  }
#pragma unroll
  for (int r = 0; r < 4; ++r)
#pragma unroll
    for (int o = 1; o <= 8; o <<= 1)
      mxv[r] = fmaxf(mxv[r], __shfl_xor(mxv[r], o, 64));

  // ---- exp, row sum, tail buckets ----
#pragma unroll
  for (int tt = 0; tt < 32; ++tt) {
    const int k = tt * 16 + cl;
#pragma unroll
    for (int r = 0; r < 4; ++r) {
      const int q = qb0 + g * 4 + r;
      const float e = __expf(sac[tt][r] - mxv[r]);
      sac[tt][r] = e;
      smv[r] += e;
      if (k <= q - 64) t0a[r] += e;
      if (k >= q + 64) t1a[r] += e;
    }
  }
#pragma unroll
  for (int r = 0; r < 4; ++r)
#pragma unroll
    for (int o = 1; o <= 8; o <<= 1) {
      smv[r] += __shfl_xor(smv[r], o, 64);
      t0a[r] += __shfl_xor(t0a[r], o, 64);
      t1a[r] += __shfl_xor(t1a[r], o, 64);
    }
  float inv[4];
#pragma unroll
  for (int r = 0; r < 4; ++r) inv[r] = 1.0f / smv[r];

  __syncthreads();   // all R reads done -> ext region reusable

  // ---- write P interior + tail buckets ----
#pragma unroll
  for (int tt = 0; tt < 32; ++tt)
#pragma unroll
    for (int r = 0; r < 4; ++r)
      Pl[g * 4 + r][tt * 16 + cl] = (__bf16)(sac[tt][r] * inv[r]);
  if (cl == 0) {
#pragma unroll
    for (int r = 0; r < 4; ++r) {
      Pl[g * 4 + r][Ss + 0]   = (__bf16)(t0a[r] * inv[r]);
      Pl[g * 4 + r][Ss + 128] = (__bf16)(t1a[r] * inv[r]);
    }
  }
  __syncthreads();   // interior P visible for gather

  // ---- Prow ext cols (gather interior P by relative bucket) ----
  {
    const int qrow = qb0 + cl;             // lane handles row cl, r = g + 4i
    for (int i = 0; i < 40; ++i) {
      const int r = g + 4 * i;
      if (r == 0 || r == 128) continue;
      float v = 0.f;
      if (r < 128) {
        const int k2 = qrow + r - 64;
        if (k2 >= 0 && k2 < Ss) v = (float)Pl[cl][k2];
      }
      Pl[cl][Ss + r] = (__bf16)v;
    }
  }
  __syncthreads();   // full P_ext visible

  // ---- ctx = P_ext @ vte^T (K = 672); vte loads pipelined 2-deep ----
  floatx4 c[4] = {};
  const __bf16* vb = Vt + (size_t)bh * DH * PLD;
  bf16x8 va0, va1, va2, va3, vn0, vn1, vn2, vn3;
  va0 = *(const bf16x8*)(vb + (size_t)(0 * 16 + cl) * PLD + g * 8);
  va1 = *(const bf16x8*)(vb + (size_t)(1 * 16 + cl) * PLD + g * 8);
  va2 = *(const bf16x8*)(vb + (size_t)(2 * 16 + cl) * PLD + g * 8);
  va3 = *(const bf16x8*)(vb + (size_t)(3 * 16 + cl) * PLD + g * 8);
#pragma unroll
  for (int kk = 0; kk < 21; ++kk) {
    if (kk < 20) {
      const int o = (kk + 1) * 32 + g * 8;
      vn0 = *(const bf16x8*)(vb + (size_t)(0 * 16 + cl) * PLD + o);
      vn1 = *(const bf16x8*)(vb + (size_t)(1 * 16 + cl) * PLD + o);
      vn2 = *(const bf16x8*)(vb + (size_t)(2 * 16 + cl) * PLD + o);
      vn3 = *(const bf16x8*)(vb + (size_t)(3 * 16 + cl) * PLD + o);
    }
    const bf16x8 pa = *(const bf16x8*)&Pl[cl][kk * 32 + g * 8];
    __builtin_amdgcn_s_setprio(1);
    c[0] = __builtin_amdgcn_mfma_f32_16x16x32_bf16(pa, va0, c[0], 0, 0, 0);
    c[1] = __builtin_amdgcn_mfma_f32_16x16x32_bf16(pa, va1, c[1], 0, 0, 0);
    c[2] = __builtin_amdgcn_mfma_f32_16x16x32_bf16(pa, va2, c[2], 0, 0, 0);
    c[3] = __builtin_amdgcn_mfma_f32_16x16x32_bf16(pa, va3, c[3], 0, 0, 0);
    __builtin_amdgcn_s_setprio(0);
    if (kk < 20) { va0 = vn0; va1 = vn1; va2 = vn2; va3 = vn3; }
  }
#pragma unroll
  for (int t2 = 0; t2 < 4; ++t2)
#pragma unroll
    for (int r = 0; r < 4; ++r)
      out[(size_t)(b * Ss + qb0 + g * 4 + r) * Dd + h * DH + t2 * 16 + cl] =
          (__bf16)c[t2][r];
}

template <typename OutT>
__global__ __launch_bounds__(256) void ln_rows(
    const __bf16* __restrict__ x, const float* __restrict__ wv,
    const float* __restrict__ bv, OutT* __restrict__ out)
{
  __shared__ float red[4];
  const int row = blockIdx.x, t = threadIdx.x;
  const __bf16* xr = x + (size_t)row * Dd;
  float xv[3], s = 0.f;
#pragma unroll
  for (int j = 0; j < 3; ++j) { xv[j] = (float)xr[t + 256 * j]; s += xv[j]; }
  s = wredsum(s);
  if ((t & 63) == 0) red[t >> 6] = s;
  __syncthreads();
  const float mean = (red[0] + red[1] + red[2] + red[3]) * (1.0f / Dd);
  __syncthreads();
  float qq = 0.f;
#pragma unroll
  for (int j = 0; j < 3; ++j) { const float d = xv[j] - mean; qq += d * d; }
  qq = wredsum(qq);
  if ((t & 63) == 0) red[t >> 6] = qq;
  __syncthreads();
  const float var = (red[0] + red[1] + red[2] + red[3]) * (1.0f / Dd);
  const float rs = rsqrtf(var + LN_EPS);
#pragma unroll
  for (int j = 0; j < 3; ++j) {
    const int i = t + 256 * j;
    out[(size_t)row * Dd + i] = (OutT)((xv[j] - mean) * rs * wv[i] + bv[i]);
  }
}

__global__ __launch_bounds__(256) void embed_ln(
    const int* __restrict__ ids, const int* __restrict__ tts,
    const float* __restrict__ we, const float* __restrict__ te,
    const float* __restrict__ wv, const float* __restrict__ bv,
    __bf16* __restrict__ out)
{
  __shared__ float red[4];
  const int row = blockIdx.x, t = threadIdx.x;
  const int id = ids[row], tt = tts[row];
  const float* wr = we + (size_t)id * Dd;
  const float* tr = te + (size_t)tt * Dd;
  float xv[3], s = 0.f;
#pragma unroll
  for (int j = 0; j < 3; ++j) {
    const int i = t + 256 * j;
    xv[j] = wr[i] + tr[i];
    s += xv[j];
  }
  s = wredsum(s);
  if ((t & 63) == 0) red[t >> 6] = s;
  __syncthreads();
  const float mean = (red[0] + red[1] + red[2] + red[3]) * (1.0f / Dd);
  __syncthreads();
  float qq = 0.f;
#pragma unroll
  for (int j = 0; j < 3; ++j) { const float d = xv[j] - mean; qq += d * d; }
  qq = wredsum(qq);
  if ((t & 63) == 0) red[t >> 6] = qq;
  __syncthreads();
  const float var = (red[0] + red[1] + red[2] + red[3]) * (1.0f / Dd);
  const float rs = rsqrtf(var + LN_EPS);
#pragma unroll
  for (int j = 0; j < 3; ++j) {
    const int i = t + 256 * j;
    out[(size_t)row * Dd + i] = (__bf16)((xv[j] - mean) * rs * wv[i] + bv[i]);
  }
}

// fp32 -> bf16 bulk convert (n % 4 == 0)
__global__ __launch_bounds__(256) void f2b(
    const float* __restrict__ in, __bf16* __restrict__ out, int n4)
{
  const int i = blockIdx.x * 256 + threadIdx.x;
  if (i >= n4) return;
  const float4 v = ((const float4*)in)[i];
  bf16x4 o;
  o[0] = (__bf16)v.x; o[1] = (__bf16)v.y; o[2] = (__bf16)v.z; o[3] = (__bf16)v.w;
  *(bf16x4*)(out + (size_t)i * 4) = o;
}

// Fill the T^T block of vte: vte[bh][d][512+r] = rel[64][r][d] (r<129), else 0.
__global__ __launch_bounds__(256) void prep_rel(
    const float* __restrict__ rel, __bf16* __restrict__ vte)
{
  const int idx = blockIdx.x * 256 + threadIdx.x;
  constexpr int TOT = BH * DH * RLD;
  if (idx >= TOT) return;
  const int r = idx % RLD, t2 = idx / RLD;
  const int d = t2 % DH, bh = t2 / DH;
  __bf16 v = (__bf16)0.f;
  if (r < 129) v = (__bf16)rel[((size_t)(64 * Ss + r)) * DH + d];
  vte[((size_t)bh * DH + d) * PLD + Ss + r] = v;
}

// Tb[r][d] = rel[64][r][d] for r<129 else 0; 192 rows (R-MFMA reads 192).
__global__ __launch_bounds__(256) void rel2b(
    const float* __restrict__ rel, __bf16* __restrict__ Tb)
{
  const int idx = blockIdx.x * 256 + threadIdx.x;  // < 192*64
  const int d = idx & 63, r = idx >> 6;
  float v = (r < 129) ? rel[((size_t)(64 * Ss + r)) * DH + d] : 0.f;
  Tb[idx] = (__bf16)v;
}

extern "C" void kernel_launch(void* const* d_in, const int* in_sizes, int n_in,
                              void* d_out, int out_size, void* d_ws, size_t ws_size,
                              hipStream_t stream)
{
  (void)in_sizes; (void)n_in; (void)out_size; (void)ws_size;
  const int*   ids  = (const int*)d_in[0];
  const int*   mask = (const int*)d_in[1];
  const int*   tts  = (const int*)d_in[2];
  const float* wemb = (const float*)d_in[3];
  const float* temb = (const float*)d_in[4];
  const float* elw  = (const float*)d_in[5];
  const float* elb  = (const float*)d_in[6];
  const float* qw   = (const float*)d_in[7];
  const float* qb   = (const float*)d_in[8];
  const float* kw   = (const float*)d_in[9];
  const float* kb   = (const float*)d_in[10];
  const float* vw   = (const float*)d_in[11];
  const float* vb   = (const float*)d_in[12];
  const float* rel  = (const float*)d_in[13];
  const float* aow  = (const float*)d_in[14];
  const float* aob  = (const float*)d_in[15];
  const float* alw  = (const float*)d_in[16];
  const float* alb  = (const float*)d_in[17];
  const float* iw   = (const float*)d_in[18];
  const float* ib   = (const float*)d_in[19];
  const float* ow   = (const float*)d_in[20];
  const float* ob   = (const float*)d_in[21];
  const float* olw  = (const float*)d_in[22];
  const float* olb  = (const float*)d_in[23];

  char* wsb = (char*)d_ws;
  size_t off = 0;
  auto alloc = [&](size_t elems) {
    __bf16* p = (__bf16*)(wsb + off);
    off += elems * sizeof(__bf16);
    return p;
  };
  constexpr size_t HB  = (size_t)Bb * Ss * Dd;         // 6.29M elems
  constexpr size_t WQ  = (size_t)Dd * Dd;              // one 768x768
  constexpr size_t WI  = (size_t)Ll * FF * Dd;         // 9.44M
  __bf16* qkvw_b = alloc((size_t)Ll * 3 * WQ);         // [l][2304][768]
  __bf16* aw_b = alloc((size_t)Ll * WQ);
  __bf16* iw_b = alloc(WI);
  __bf16* ow_b = alloc(WI);
  __bf16* hbuf = alloc(HB);                            // hidden state
  __bf16* abuf = alloc(HB);                            // attn-LN output
  __bf16* qbuf = alloc(HB);                            // also aliased as s1
  __bf16* kbuf = alloc(HB);
  __bf16* ctx  = alloc(HB);
  __bf16* vte  = alloc((size_t)BH * DH * PLD);         // [V^T | T^T] per (b,h)
  __bf16* fbuf = alloc((size_t)Bb * Ss * FF);          // GELU out
  __bf16* Tb   = alloc((size_t)192 * DH);              // bf16 rel table
  __bf16* s1   = qbuf;                                 // alias: free after attn

  // weight converts: QKV interleaved per layer as [Q(768)|K(768)|V(768)] x 768
  for (int l = 0; l < Ll; ++l) {
    f2b<<<(int)((WQ / 4 + 255) / 256), 256, 0, stream>>>(
        qw + (size_t)l * WQ, qkvw_b + ((size_t)l * 3 + 0) * WQ, (int)(WQ / 4));
    f2b<<<(int)((WQ / 4 + 255) / 256), 256, 0, stream>>>(
        kw + (size_t)l * WQ, qkvw_b + ((size_t)l * 3 + 1) * WQ, (int)(WQ / 4));
    f2b<<<(int)((WQ / 4 + 255) / 256), 256, 0, stream>>>(
        vw + (size_t)l * WQ, qkvw_b + ((size_t)l * 3 + 2) * WQ, (int)(WQ / 4));
  }
  f2b<<<(int)((Ll * WQ / 4 + 255) / 256), 256, 0, stream>>>(aow, aw_b, (int)(Ll * WQ / 4));
  f2b<<<(int)((WI / 4 + 255) / 256), 256, 0, stream>>>(iw, iw_b, (int)(WI / 4));
  f2b<<<(int)((WI / 4 + 255) / 256), 256, 0, stream>>>(ow, ow_b, (int)(WI / 4));
  rel2b<<<(192 * DH) / 256, 256, 0, stream>>>(rel, Tb);
  prep_rel<<<(BH * DH * RLD + 255) / 256, 256, 0, stream>>>(rel, vte);
  embed_ln<<<Bb * Ss, 256, 0, stream>>>(ids, tts, wemb, temb, elw, elb, hbuf);

  for (int l = 0; l < Ll; ++l) {
    const __bf16* qkvwl = qkvw_b + (size_t)l * 3 * WQ;
    const float*  qbl = qb + (size_t)l * Dd;
    const float*  kbl = kb + (size_t)l * Dd;
    const float*  vbl = vb + (size_t)l * Dd;
    const __bf16* awl = aw_b + (size_t)l * WQ;       const float* abl = aob + (size_t)l * Dd;
    const float*  lw1 = alw + (size_t)l * Dd;        const float* lb1 = alb + (size_t)l * Dd;
    const __bf16* iwl = iw_b + (size_t)l * FF * Dd;  const float* ibl = ib + (size_t)l * FF;
    const __bf16* owl = ow_b + (size_t)l * FF * Dd;  const float* obl = ob + (size_t)l * Dd;
    const float*  lw2 = olw + (size_t)l * Dd;        const float* lb2 = olb + (size_t)l * Dd;

    // fused QKV: (8192 x 2304) = hbuf @ [q|k|v]^T, writes qbuf, kbuf, vte
    gemm128<E_QKV, 2304, 768><<<64 * 18, 256, 0, stream>>>(
        hbuf, qkvwl, qbl, kbl, vbl, nullptr, qbuf, kbuf, vte);
    // fused attention middle: scores + rel + softmax + Prow + PV -> ctx
    attn_fused<<<6144, 64, 0, stream>>>(qbuf, kbuf, vte, Tb, mask, ctx);
    gemm128<E_RES, 768, 768><<<64 * 6, 256, 0, stream>>>(
        ctx, awl, abl, nullptr, nullptr, hbuf, s1, nullptr, nullptr);
    ln_rows<__bf16><<<8192, 256, 0, stream>>>(s1, lw1, lb1, abuf);
    gemm128<E_GELU, 3072, 768><<<64 * 24, 256, 0, stream>>>(
        abuf, iwl, ibl, nullptr, nullptr, nullptr, fbuf, nullptr, nullptr);
    gemm128<E_RES, 768, 3072><<<64 * 6, 256, 0, stream>>>(
        fbuf, owl, obl, nullptr, nullptr, abuf, s1, nullptr, nullptr);
    if (l == Ll - 1)
      ln_rows<float><<<8192, 256, 0, stream>>>(s1, lw2, lb2, (float*)d_out);
    else
      ln_rows<__bf16><<<8192, 256, 0, stream>>>(s1, lw2, lb2, hbuf);
  }
}

// Round 6
// 1824.180 us; speedup vs baseline: 1.1198x; 1.1198x over previous
//
#include <hip/hip_runtime.h>
#include <hip/hip_bf16.h>
#include <math.h>

// NEZHA-style 4-layer encoder, B=16 S=512 D=768 H=12 DH=64 FF=3072.
// Reference dtypes: float32 in / float32 out. Internal compute: bf16 MFMA.
// R3: m97-style 128x128 LDS-staged GEMM for the big GEMMs; fused QKV.
// R4/R6: fused attention middle (scores + rel gather + softmax + Prow + PV).
// R7: XCD-chunked grid (FETCH 120->20.7MB) -- still latency-bound.
// R8: 1-wave blocks, direct-L2 K: NO change (166us) => per-wave serial
//     latency x 3.7 resident waves is the binding constraint (VALUBusy
//     scaled exactly with occupancy).
// R9: 4-wave cooperative blocks: k-split QK^T (sac 128->32 VGPR), LDS
//     combine for max/sum/tails, n-split R/gather/PV.  launch_bounds(256,4)
//     + 23.3KB LDS => ~16 resident waves/CU (4.3x) and 4x shorter chains.

typedef __bf16 bf16x8 __attribute__((ext_vector_type(8)));
typedef __bf16 bf16x4 __attribute__((ext_vector_type(4)));
typedef float  floatx4 __attribute__((ext_vector_type(4)));

constexpr int Bb = 16, Ss = 512, Dd = 768, Hh = 12, DH = 64, FF = 3072, Ll = 4;
constexpr int BH  = Bb * Hh;       // 192 (batch*heads)
constexpr int RLD = 160;           // padded rel-bucket dim (129 -> 160)
constexpr int PLD = Ss + RLD;      // 672: [V^T | T^T] inner dim
constexpr float LN_EPS = 1e-12f;

__device__ inline float wredsum(float v) {
#pragma unroll
  for (int o = 32; o > 0; o >>= 1) v += __shfl_xor(v, o, 64);
  return v;
}

__device__ inline void gload_lds16(const __bf16* gp, __bf16* lp) {
  __builtin_amdgcn_global_load_lds(
      (const __attribute__((address_space(1))) void*)gp,
      (__attribute__((address_space(3))) void*)lp, 16, 0, 0);
}

enum { E_QKV, E_RES, E_GELU };

// ---------------------------------------------------------------------------
// m97-style LDS-staged GEMM: C(M,N) = A(M,K) @ B(N,K)^T.  Block = 256 thr =
// 4 waves; 128x128 C-tile; each wave 64x64 (4x4 MFMA 16x16x32 acc).  BK=64
// staged via global_load_lds dwordx4 (wave-uniform LDS base + lane*16).
// Grid is always a multiple of 8 -> XCD-chunked swizzle is bijective.
// ---------------------------------------------------------------------------
template <int EPI, int N, int K>
__global__ __launch_bounds__(256) void gemm128(
    const __bf16* __restrict__ A, const __bf16* __restrict__ B,
    const float* __restrict__ b0, const float* __restrict__ b1,
    const float* __restrict__ b2, const __bf16* __restrict__ aux,
    __bf16* __restrict__ o0, __bf16* __restrict__ o1, __bf16* __restrict__ o2)
{
  __shared__ __bf16 As[128 * 64];
  __shared__ __bf16 Bs[128 * 64];
  const int t = threadIdx.x;
  const int lane = t & 63, wid = t >> 6;
  constexpr int NT = N / 128;
  const int nwg = (int)gridDim.x;
  const int cpx = nwg >> 3;
  const int bid = (int)blockIdx.x;
  const int swz = (bid & 7) * cpx + (bid >> 3);
  const int tm = swz / NT, tn = swz % NT;

  const __bf16* Ag = A + (size_t)(tm * 128) * K;
  const __bf16* Bg = B + (size_t)(tn * 128) * K;

  const int srow = t >> 3;          // 0..31: staged row within 32-row chunk
  const int scol = (t & 7) * 8;     // k-offset of this thread's 16B

  const int wm = (wid >> 1) * 64, wn = (wid & 1) * 64;
  const int fr = lane & 15, fk = (lane >> 4) * 8;

  floatx4 acc[4][4] = {};

  for (int k0 = 0; k0 < K; k0 += 64) {
    __syncthreads();
#pragma unroll
    for (int j = 0; j < 4; ++j) {
      const int row = j * 32 + srow;
      const int ldsrow = j * 32 + wid * 8;              // wave-uniform base row
      gload_lds16(Ag + (size_t)row * K + k0 + scol, As + ldsrow * 64);
      gload_lds16(Bg + (size_t)row * K + k0 + scol, Bs + ldsrow * 64);
    }
    __syncthreads();
#pragma unroll
    for (int kk = 0; kk < 64; kk += 32) {
      bf16x8 af[4], bfv[4];
#pragma unroll
      for (int i = 0; i < 4; ++i) {
        af[i]  = *(const bf16x8*)(As + (wm + i * 16 + fr) * 64 + kk + fk);
        bfv[i] = *(const bf16x8*)(Bs + (wn + i * 16 + fr) * 64 + kk + fk);
      }
#pragma unroll
      for (int i = 0; i < 4; ++i)
#pragma unroll
        for (int j = 0; j < 4; ++j)
          acc[i][j] = __builtin_amdgcn_mfma_f32_16x16x32_bf16(af[i], bfv[j],
                                                              acc[i][j], 0, 0, 0);
    }
  }

  const int rbase = (lane >> 4) << 2;
  const int cl = lane & 15;

  if constexpr (EPI == E_QKV) {
    // N = 2304 = [Q(768) | K(768) | V(768)]; 128-tiles never cross a 768 edge.
    const int which = (tn * 128) / Dd;
    const float* bias = which == 0 ? b0 : (which == 1 ? b1 : b2);
#pragma unroll
    for (int j = 0; j < 4; ++j) {
      const int col = tn * 128 + wn + j * 16 + cl - which * Dd;
      const float bv = bias[col];
#pragma unroll
      for (int i = 0; i < 4; ++i)
#pragma unroll
        for (int r = 0; r < 4; ++r) {
          const int m = tm * 128 + wm + i * 16 + rbase + r;
          const float v = acc[i][j][r] + bv;
          if (which == 2) {   // V -> transposed [V^T | T^T] layout
            const int hh = col >> 6, d = col & 63;
            const int bb = m >> 9, s = m & 511;
            o2[((size_t)(bb * Hh + hh) * DH + d) * PLD + s] = (__bf16)v;
          } else {
            (which == 0 ? o0 : o1)[(size_t)m * Dd + col] = (__bf16)v;
          }
        }
    }
  } else if constexpr (EPI == E_RES) {
#pragma unroll
    for (int j = 0; j < 4; ++j) {
      const int n = tn * 128 + wn + j * 16 + cl;
      const float bv = b0[n];
#pragma unroll
      for (int i = 0; i < 4; ++i)
#pragma unroll
        for (int r = 0; r < 4; ++r) {
          const int m = tm * 128 + wm + i * 16 + rbase + r;
          o0[(size_t)m * Dd + n] =
              (__bf16)(acc[i][j][r] + bv + (float)aux[(size_t)m * Dd + n]);
        }
    }
  } else if constexpr (EPI == E_GELU) {
#pragma unroll
    for (int j = 0; j < 4; ++j) {
      const int n = tn * 128 + wn + j * 16 + cl;
      const float bv = b0[n];
#pragma unroll
      for (int i = 0; i < 4; ++i)
#pragma unroll
        for (int r = 0; r < 4; ++r) {
          const int m = tm * 128 + wm + i * 16 + rbase + r;
          const float x = acc[i][j][r] + bv;
          o0[(size_t)m * FF + n] =
              (__bf16)(0.5f * x * (1.0f + erff(x * 0.7071067811865475f)));
        }
    }
  }
}

// ---------------------------------------------------------------------------
// Fused attention middle, 4-wave cooperative.  Grid = 6144 1-D (XCD-chunked),
// block = 256 thr = 4 waves; block owns (bh, 16 q-rows).  Work split:
//   QK^T : wave w -> k in [w*128, w*128+128)   (sac[8] = 32 VGPR)
//   R    : wave w -> rel cols [w*48, w*48+48)
//   softmax: per-wave partials, combined via 1KB LDS (2 barriers)
//   gather : wave w -> ext cols r == (w*4+g) mod 16
//   PV   : wave w -> output cols [w*16, w*16+16), full K=672, acc = 4 VGPR
// LDS = Pl 22.3KB + 1KB combine -> 6 blocks/CU; launch_bounds(256,4) caps
// VGPR<=128 -> ~16 resident waves/CU (vs 3.7 in R8).
// ---------------------------------------------------------------------------
__global__ __launch_bounds__(256, 4) void attn_fused(
    const __bf16* __restrict__ Q, const __bf16* __restrict__ Kb,
    const __bf16* __restrict__ Vt, const __bf16* __restrict__ Tb,
    const int* __restrict__ mask, __bf16* __restrict__ out)
{
  __shared__ __bf16 Pl[16][696];      // [P interior 512 | ext 160], pad 696
  __shared__ float sm_max[4][16], sm_sum[4][16], sm_t0[4][16], sm_t1[4][16];

  const int t = threadIdx.x;
  const int lane = t & 63, w = t >> 6;
  const int cl = lane & 15, g = lane >> 4;
  const int bid = (int)blockIdx.x;
  const int swz = (bid & 7) * (6144 / 8) + (bid >> 3);
  const int qt = swz & 31, bh = swz >> 5;
  const int b = bh / Hh, h = bh % Hh;
  const int qb0 = qt * 16;
  const int row0 = g * 4;             // this lane's 4 q-rows: row0..row0+3

  // Q fragments (A operand): row = cl, k = g*8 + j (+32 for second k-step)
  const __bf16* qp = Q + (size_t)(b * Ss + qb0 + cl) * Dd + h * DH + g * 8;
  const bf16x8 aq0 = *(const bf16x8*)qp;
  const bf16x8 aq1 = *(const bf16x8*)(qp + 32);

  // ---- scores S = Q @ K^T for this wave's 128-k slab (direct, L2-hot) ----
  floatx4 sac[8] = {};
  const __bf16* kbase = Kb + (size_t)(b * Ss) * Dd + h * DH + g * 8;
  __builtin_amdgcn_s_setprio(1);
#pragma unroll
  for (int tt = 0; tt < 8; ++tt) {
    const __bf16* kp = kbase + (size_t)(w * 128 + tt * 16 + cl) * Dd;
    const bf16x8 b0 = *(const bf16x8*)kp;
    const bf16x8 b1 = *(const bf16x8*)(kp + 32);
    sac[tt] = __builtin_amdgcn_mfma_f32_16x16x32_bf16(aq0, b0, sac[tt], 0, 0, 0);
    sac[tt] = __builtin_amdgcn_mfma_f32_16x16x32_bf16(aq1, b1, sac[tt], 0, 0, 0);
  }
  __builtin_amdgcn_s_setprio(0);

  // ---- R = Q @ Tb^T, this wave's 48 cols (cols >=132 unused) ----
  {
    floatx4 rac[3] = {};
#pragma unroll
    for (int j = 0; j < 3; ++j) {
      const __bf16* bp = Tb + (size_t)((w * 3 + j) * 16 + cl) * DH + g * 8;
      const bf16x8 b0 = *(const bf16x8*)bp;
      const bf16x8 b1 = *(const bf16x8*)(bp + 32);
      rac[j] = __builtin_amdgcn_mfma_f32_16x16x32_bf16(aq0, b0, rac[j], 0, 0, 0);
      rac[j] = __builtin_amdgcn_mfma_f32_16x16x32_bf16(aq1, b1, rac[j], 0, 0, 0);
    }
#pragma unroll
    for (int j = 0; j < 3; ++j) {
      const int col = (w * 3 + j) * 16 + cl;
      if (col < 132) {
#pragma unroll
        for (int r = 0; r < 4; ++r) Pl[row0 + r][Ss + col] = (__bf16)rac[j][r];
      }
    }
  }
  __syncthreads();   // R visible to all waves

  // ---- rel gather + scale + mask; per-wave partial row max ----
  float mxv[4];
#pragma unroll
  for (int r = 0; r < 4; ++r) mxv[r] = -3.0e38f;
#pragma unroll
  for (int tt = 0; tt < 8; ++tt) {
    const int k = w * 128 + tt * 16 + cl;
    const float mbk = (1.0f - (float)mask[b * Ss + k]) * -10000.0f;
#pragma unroll
    for (int r = 0; r < 4; ++r) {
      const int ql = row0 + r;
      int rr = k - (qb0 + ql);
      rr = rr < -64 ? -64 : (rr > 64 ? 64 : rr);
      const float s = (sac[tt][r] + (float)Pl[ql][Ss + rr + 64]) * 0.125f + mbk;
      sac[tt][r] = s;
      mxv[r] = fmaxf(mxv[r], s);
    }
  }
#pragma unroll
  for (int r = 0; r < 4; ++r)
#pragma unroll
    for (int o = 1; o <= 8; o <<= 1)
      mxv[r] = fmaxf(mxv[r], __shfl_xor(mxv[r], o, 64));
  if (cl == 0) {
#pragma unroll
    for (int r = 0; r < 4; ++r) sm_max[w][row0 + r] = mxv[r];
  }
  __syncthreads();   // partial maxes visible

  float mxf[4];
#pragma unroll
  for (int r = 0; r < 4; ++r)
    mxf[r] = fmaxf(fmaxf(sm_max[0][row0 + r], sm_max[1][row0 + r]),
                   fmaxf(sm_max[2][row0 + r], sm_max[3][row0 + r]));

  // ---- exp, partial row sum + tail buckets ----
  float smv[4], t0a[4], t1a[4];
#pragma unroll
  for (int r = 0; r < 4; ++r) { smv[r] = t0a[r] = t1a[r] = 0.f; }
#pragma unroll
  for (int tt = 0; tt < 8; ++tt) {
    const int k = w * 128 + tt * 16 + cl;
#pragma unroll
    for (int r = 0; r < 4; ++r) {
      const int q = qb0 + row0 + r;
      const float e = __expf(sac[tt][r] - mxf[r]);
      sac[tt][r] = e;
      smv[r] += e;
      if (k <= q - 64) t0a[r] += e;
      if (k >= q + 64) t1a[r] += e;
    }
  }
#pragma unroll
  for (int r = 0; r < 4; ++r)
#pragma unroll
    for (int o = 1; o <= 8; o <<= 1) {
      smv[r] += __shfl_xor(smv[r], o, 64);
      t0a[r] += __shfl_xor(t0a[r], o, 64);
      t1a[r] += __shfl_xor(t1a[r], o, 64);
    }
  if (cl == 0) {
#pragma unroll
    for (int r = 0; r < 4; ++r) {
      sm_sum[w][row0 + r] = smv[r];
      sm_t0[w][row0 + r]  = t0a[r];
      sm_t1[w][row0 + r]  = t1a[r];
    }
  }
  __syncthreads();   // partial sums visible; all R reads complete

  float inv[4], t0f[4], t1f[4];
#pragma unroll
  for (int r = 0; r < 4; ++r) {
    const int q = row0 + r;
    const float s = sm_sum[0][q] + sm_sum[1][q] + sm_sum[2][q] + sm_sum[3][q];
    inv[r] = 1.0f / s;
    t0f[r] = sm_t0[0][q] + sm_t0[1][q] + sm_t0[2][q] + sm_t0[3][q];
    t1f[r] = sm_t1[0][q] + sm_t1[1][q] + sm_t1[2][q] + sm_t1[3][q];
  }

  // ---- write P interior (this wave's 128 cols) + tails (wave 0) ----
#pragma unroll
  for (int tt = 0; tt < 8; ++tt)
#pragma unroll
    for (int r = 0; r < 4; ++r)
      Pl[row0 + r][w * 128 + tt * 16 + cl] = (__bf16)(sac[tt][r] * inv[r]);
  if (w == 0 && cl == 0) {
#pragma unroll
    for (int r = 0; r < 4; ++r) {
      Pl[row0 + r][Ss + 0]   = (__bf16)(t0f[r] * inv[r]);
      Pl[row0 + r][Ss + 128] = (__bf16)(t1f[r] * inv[r]);
    }
  }
  __syncthreads();   // interior P + tails visible

  // ---- Prow ext cols (gather interior P by relative bucket) ----
  {
    const int qrow = qb0 + cl;           // lane handles row cl
#pragma unroll
    for (int i = 0; i < 10; ++i) {
      const int r = (w * 4 + g) + 16 * i;     // covers 0..159 exactly once
      if (r == 0 || r == 128) continue;
      float v = 0.f;
      if (r < 128) {
        const int k2 = qrow + r - 64;
        if (k2 >= 0 && k2 < Ss) v = (float)Pl[cl][k2];
      }
      Pl[cl][Ss + r] = (__bf16)v;
    }
  }
  __syncthreads();   // full P_ext visible

  // ---- ctx = P_ext @ vte^T: wave w -> output cols [w*16, +16), K=672 ----
  floatx4 c = {};
  const __bf16* vb = Vt + (size_t)bh * DH * PLD + (size_t)(w * 16 + cl) * PLD + g * 8;
  bf16x8 va = *(const bf16x8*)vb;
#pragma unroll
  for (int kk = 0; kk < 21; ++kk) {
    bf16x8 vn;
    if (kk < 20) vn = *(const bf16x8*)(vb + (kk + 1) * 32);
    const bf16x8 pa = *(const bf16x8*)&Pl[cl][kk * 32 + g * 8];
    c = __builtin_amdgcn_mfma_f32_16x16x32_bf16(pa, va, c, 0, 0, 0);
    if (kk < 20) va = vn;
  }
#pragma unroll
  for (int r = 0; r < 4; ++r)
    out[(size_t)(b * Ss + qb0 + row0 + r) * Dd + h * DH + w * 16 + cl] =
        (__bf16)c[r];
}

template <typename OutT>
__global__ __launch_bounds__(256) void ln_rows(
    const __bf16* __restrict__ x, const float* __restrict__ wv,
    const float* __restrict__ bv, OutT* __restrict__ out)
{
  __shared__ float red[4];
  const int row = blockIdx.x, t = threadIdx.x;
  const __bf16* xr = x + (size_t)row * Dd;
  float xv[3], s = 0.f;
#pragma unroll
  for (int j = 0; j < 3; ++j) { xv[j] = (float)xr[t + 256 * j]; s += xv[j]; }
  s = wredsum(s);
  if ((t & 63) == 0) red[t >> 6] = s;
  __syncthreads();
  const float mean = (red[0] + red[1] + red[2] + red[3]) * (1.0f / Dd);
  __syncthreads();
  float qq = 0.f;
#pragma unroll
  for (int j = 0; j < 3; ++j) { const float d = xv[j] - mean; qq += d * d; }
  qq = wredsum(qq);
  if ((t & 63) == 0) red[t >> 6] = qq;
  __syncthreads();
  const float var = (red[0] + red[1] + red[2] + red[3]) * (1.0f / Dd);
  const float rs = rsqrtf(var + LN_EPS);
#pragma unroll
  for (int j = 0; j < 3; ++j) {
    const int i = t + 256 * j;
    out[(size_t)row * Dd + i] = (OutT)((xv[j] - mean) * rs * wv[i] + bv[i]);
  }
}

__global__ __launch_bounds__(256) void embed_ln(
    const int* __restrict__ ids, const int* __restrict__ tts,
    const float* __restrict__ we, const float* __restrict__ te,
    const float* __restrict__ wv, const float* __restrict__ bv,
    __bf16* __restrict__ out)
{
  __shared__ float red[4];
  const int row = blockIdx.x, t = threadIdx.x;
  const int id = ids[row], tt = tts[row];
  const float* wr = we + (size_t)id * Dd;
  const float* tr = te + (size_t)tt * Dd;
  float xv[3], s = 0.f;
#pragma unroll
  for (int j = 0; j < 3; ++j) {
    const int i = t + 256 * j;
    xv[j] = wr[i] + tr[i];
    s += xv[j];
  }
  s = wredsum(s);
  if ((t & 63) == 0) red[t >> 6] = s;
  __syncthreads();
  const float mean = (red[0] + red[1] + red[2] + red[3]) * (1.0f / Dd);
  __syncthreads();
  float qq = 0.f;
#pragma unroll
  for (int j = 0; j < 3; ++j) { const float d = xv[j] - mean; qq += d * d; }
  qq = wredsum(qq);
  if ((t & 63) == 0) red[t >> 6] = qq;
  __syncthreads();
  const float var = (red[0] + red[1] + red[2] + red[3]) * (1.0f / Dd);
  const float rs = rsqrtf(var + LN_EPS);
#pragma unroll
  for (int j = 0; j < 3; ++j) {
    const int i = t + 256 * j;
    out[(size_t)row * Dd + i] = (__bf16)((xv[j] - mean) * rs * wv[i] + bv[i]);
  }
}

// fp32 -> bf16 bulk convert (n % 4 == 0)
__global__ __launch_bounds__(256) void f2b(
    const float* __restrict__ in, __bf16* __restrict__ out, int n4)
{
  const int i = blockIdx.x * 256 + threadIdx.x;
  if (i >= n4) return;
  const float4 v = ((const float4*)in)[i];
  bf16x4 o;
  o[0] = (__bf16)v.x; o[1] = (__bf16)v.y; o[2] = (__bf16)v.z; o[3] = (__bf16)v.w;
  *(bf16x4*)(out + (size_t)i * 4) = o;
}

// Fill the T^T block of vte: vte[bh][d][512+r] = rel[64][r][d] (r<129), else 0.
__global__ __launch_bounds__(256) void prep_rel(
    const float* __restrict__ rel, __bf16* __restrict__ vte)
{
  const int idx = blockIdx.x * 256 + threadIdx.x;
  constexpr int TOT = BH * DH * RLD;
  if (idx >= TOT) return;
  const int r = idx % RLD, t2 = idx / RLD;
  const int d = t2 % DH, bh = t2 / DH;
  __bf16 v = (__bf16)0.f;
  if (r < 129) v = (__bf16)rel[((size_t)(64 * Ss + r)) * DH + d];
  vte[((size_t)bh * DH + d) * PLD + Ss + r] = v;
}

// Tb[r][d] = rel[64][r][d] for r<129 else 0; 192 rows (R-MFMA reads 192).
__global__ __launch_bounds__(256) void rel2b(
    const float* __restrict__ rel, __bf16* __restrict__ Tb)
{
  const int idx = blockIdx.x * 256 + threadIdx.x;  // < 192*64
  const int d = idx & 63, r = idx >> 6;
  float v = (r < 129) ? rel[((size_t)(64 * Ss + r)) * DH + d] : 0.f;
  Tb[idx] = (__bf16)v;
}

extern "C" void kernel_launch(void* const* d_in, const int* in_sizes, int n_in,
                              void* d_out, int out_size, void* d_ws, size_t ws_size,
                              hipStream_t stream)
{
  (void)in_sizes; (void)n_in; (void)out_size; (void)ws_size;
  const int*   ids  = (const int*)d_in[0];
  const int*   mask = (const int*)d_in[1];
  const int*   tts  = (const int*)d_in[2];
  const float* wemb = (const float*)d_in[3];
  const float* temb = (const float*)d_in[4];
  const float* elw  = (const float*)d_in[5];
  const float* elb  = (const float*)d_in[6];
  const float* qw   = (const float*)d_in[7];
  const float* qb   = (const float*)d_in[8];
  const float* kw   = (const float*)d_in[9];
  const float* kb   = (const float*)d_in[10];
  const float* vw   = (const float*)d_in[11];
  const float* vb   = (const float*)d_in[12];
  const float* rel  = (const float*)d_in[13];
  const float* aow  = (const float*)d_in[14];
  const float* aob  = (const float*)d_in[15];
  const float* alw  = (const float*)d_in[16];
  const float* alb  = (const float*)d_in[17];
  const float* iw   = (const float*)d_in[18];
  const float* ib   = (const float*)d_in[19];
  const float* ow   = (const float*)d_in[20];
  const float* ob   = (const float*)d_in[21];
  const float* olw  = (const float*)d_in[22];
  const float* olb  = (const float*)d_in[23];

  char* wsb = (char*)d_ws;
  size_t off = 0;
  auto alloc = [&](size_t elems) {
    __bf16* p = (__bf16*)(wsb + off);
    off += elems * sizeof(__bf16);
    return p;
  };
  constexpr size_t HB  = (size_t)Bb * Ss * Dd;         // 6.29M elems
  constexpr size_t WQ  = (size_t)Dd * Dd;              // one 768x768
  constexpr size_t WI  = (size_t)Ll * FF * Dd;         // 9.44M
  __bf16* qkvw_b = alloc((size_t)Ll * 3 * WQ);         // [l][2304][768]
  __bf16* aw_b = alloc((size_t)Ll * WQ);
  __bf16* iw_b = alloc(WI);
  __bf16* ow_b = alloc(WI);
  __bf16* hbuf = alloc(HB);                            // hidden state
  __bf16* abuf = alloc(HB);                            // attn-LN output
  __bf16* qbuf = alloc(HB);                            // also aliased as s1
  __bf16* kbuf = alloc(HB);
  __bf16* ctx  = alloc(HB);
  __bf16* vte  = alloc((size_t)BH * DH * PLD);         // [V^T | T^T] per (b,h)
  __bf16* fbuf = alloc((size_t)Bb * Ss * FF);          // GELU out
  __bf16* Tb   = alloc((size_t)192 * DH);              // bf16 rel table
  __bf16* s1   = qbuf;                                 // alias: free after attn

  // weight converts: QKV interleaved per layer as [Q(768)|K(768)|V(768)] x 768
  for (int l = 0; l < Ll; ++l) {
    f2b<<<(int)((WQ / 4 + 255) / 256), 256, 0, stream>>>(
        qw + (size_t)l * WQ, qkvw_b + ((size_t)l * 3 + 0) * WQ, (int)(WQ / 4));
    f2b<<<(int)((WQ / 4 + 255) / 256), 256, 0, stream>>>(
        kw + (size_t)l * WQ, qkvw_b + ((size_t)l * 3 + 1) * WQ, (int)(WQ / 4));
    f2b<<<(int)((WQ / 4 + 255) / 256), 256, 0, stream>>>(
        vw + (size_t)l * WQ, qkvw_b + ((size_t)l * 3 + 2) * WQ, (int)(WQ / 4));
  }
  f2b<<<(int)((Ll * WQ / 4 + 255) / 256), 256, 0, stream>>>(aow, aw_b, (int)(Ll * WQ / 4));
  f2b<<<(int)((WI / 4 + 255) / 256), 256, 0, stream>>>(iw, iw_b, (int)(WI / 4));
  f2b<<<(int)((WI / 4 + 255) / 256), 256, 0, stream>>>(ow, ow_b, (int)(WI / 4));
  rel2b<<<(192 * DH) / 256, 256, 0, stream>>>(rel, Tb);
  prep_rel<<<(BH * DH * RLD + 255) / 256, 256, 0, stream>>>(rel, vte);
  embed_ln<<<Bb * Ss, 256, 0, stream>>>(ids, tts, wemb, temb, elw, elb, hbuf);

  for (int l = 0; l < Ll; ++l) {
    const __bf16* qkvwl = qkvw_b + (size_t)l * 3 * WQ;
    const float*  qbl = qb + (size_t)l * Dd;
    const float*  kbl = kb + (size_t)l * Dd;
    const float*  vbl = vb + (size_t)l * Dd;
    const __bf16* awl = aw_b + (size_t)l * WQ;       const float* abl = aob + (size_t)l * Dd;
    const float*  lw1 = alw + (size_t)l * Dd;        const float* lb1 = alb + (size_t)l * Dd;
    const __bf16* iwl = iw_b + (size_t)l * FF * Dd;  const float* ibl = ib + (size_t)l * FF;
    const __bf16* owl = ow_b + (size_t)l * FF * Dd;  const float* obl = ob + (size_t)l * Dd;
    const float*  lw2 = olw + (size_t)l * Dd;        const float* lb2 = olb + (size_t)l * Dd;

    // fused QKV: (8192 x 2304) = hbuf @ [q|k|v]^T, writes qbuf, kbuf, vte
    gemm128<E_QKV, 2304, 768><<<64 * 18, 256, 0, stream>>>(
        hbuf, qkvwl, qbl, kbl, vbl, nullptr, qbuf, kbuf, vte);
    // fused attention middle: scores + rel + softmax + Prow + PV -> ctx
    attn_fused<<<6144, 256, 0, stream>>>(qbuf, kbuf, vte, Tb, mask, ctx);
    gemm128<E_RES, 768, 768><<<64 * 6, 256, 0, stream>>>(
        ctx, awl, abl, nullptr, nullptr, hbuf, s1, nullptr, nullptr);
    ln_rows<__bf16><<<8192, 256, 0, stream>>>(s1, lw1, lb1, abuf);
    gemm128<E_GELU, 3072, 768><<<64 * 24, 256, 0, stream>>>(
        abuf, iwl, ibl, nullptr, nullptr, nullptr, fbuf, nullptr, nullptr);
    gemm128<E_RES, 768, 3072><<<64 * 6, 256, 0, stream>>>(
        fbuf, owl, obl, nullptr, nullptr, abuf, s1, nullptr, nullptr);
    if (l == Ll - 1)
      ln_rows<float><<<8192, 256, 0, stream>>>(s1, lw2, lb2, (float*)d_out);
    else
      ln_rows<__bf16><<<8192, 256, 0, stream>>>(s1, lw2, lb2, hbuf);
  }
}